// Round 6
// baseline (344.811 us; speedup 1.0000x reference)
//
#include <hip/hip_runtime.h>

// ---------------------------------------------------------------------------
// AdaptiveAttention: B=4,S=2048,D=1024,H=16,E=64
// R6: gemm_qkv ported to the 256x256 8-phase template (T3+T4+T5):
//     512 thr / 8 waves (2Mx4N), BK=64, 128KB LDS dbuf, per-phase raw
//     s_barrier pairs + setprio around MFMA clusters, staging windows
//     ph1-4 -> bufB(T2i+1), ph5-8 -> bufA(T2i+2), vmcnt(0) only at ph4/ph8
//     (exactly-counted: nothing else in flight). XOR-8 chunk swizzle on
//     128B LDS rows (conflict-free in 8-lane groups), inverse-swizzled
//     global source (both-sides rule). attn/gemm_out/cvt/pack unchanged.
// ---------------------------------------------------------------------------

typedef __attribute__((ext_vector_type(8))) short     s16x8;
typedef __attribute__((ext_vector_type(4))) float     f32x4;
typedef __attribute__((ext_vector_type(8))) unsigned short u16x8;
typedef __attribute__((ext_vector_type(4))) unsigned short u16x4;
typedef __attribute__((ext_vector_type(4))) unsigned int   u32x4;

#define GLD16(g, l) __builtin_amdgcn_global_load_lds(                         \
    (const __attribute__((address_space(1))) void*)(g),                       \
    (__attribute__((address_space(3))) void*)(l), 16, 0, 0)

__device__ __forceinline__ unsigned short f2bf(float f) {
  unsigned u = __builtin_bit_cast(unsigned, f);
  u += 0x7fffu + ((u >> 16) & 1u);   // round-to-nearest-even
  return (unsigned short)(u >> 16);
}

__device__ __forceinline__ f32x4 mfma16(s16x8 a, s16x8 b, f32x4 c) {
  return __builtin_amdgcn_mfma_f32_16x16x32_bf16(a, b, c, 0, 0, 0);
}

// --------------------------- conversion (fused q/k/v) -----------------------

__global__ __launch_bounds__(256) void cvt_all(
    const float* __restrict__ q, const float* __restrict__ k,
    const float* __restrict__ v, unsigned short* __restrict__ xq,
    unsigned short* __restrict__ xk, unsigned short* __restrict__ xv) {
  const int z = blockIdx.y;
  const float* in = z == 0 ? q : z == 1 ? k : v;
  unsigned short* out = z == 0 ? xq : z == 1 ? xk : xv;
  const int i = blockIdx.x * 256 + threadIdx.x;   // 0..1048575
  const float4* p = (const float4*)in;
  float4 a = p[(size_t)i * 2], b = p[(size_t)i * 2 + 1];
  u16x8 r = { f2bf(a.x), f2bf(a.y), f2bf(a.z), f2bf(a.w),
              f2bf(b.x), f2bf(b.y), f2bf(b.z), f2bf(b.w) };
  *(u16x8*)(out + (size_t)i * 8) = r;
}

// --------------------- weight packing: coalesced transpose ------------------
__global__ __launch_bounds__(256) void pack_all(
    const float* __restrict__ Wq, const float* __restrict__ Wk,
    const float* __restrict__ Wv, const float* __restrict__ Wo,
    unsigned short* __restrict__ WQT, unsigned short* __restrict__ WKT,
    unsigned short* __restrict__ WVT, unsigned short* __restrict__ WOT) {
  __shared__ float t[64][65];
  const int z = blockIdx.z, xb = blockIdx.x, kb = blockIdx.y;
  const int tid = threadIdx.x, kr = tid >> 2, q4 = tid & 3;

  const float* srcp;
  size_t srs;
  if (z < 3) {
    const float* W = z == 0 ? Wq : z == 1 ? Wk : Wv;
    srcp = W + (size_t)xb * 65536 + (size_t)kb * 4096;   // [k0+kr][col], stride 64
    srs = 64;
  } else {
    srcp = Wo + (size_t)kb * 65536 + (size_t)xb * 64;    // [k0+kr][n0+col], stride 1024
    srs = 1024;
  }
  unsigned short* dstb =
      (z == 0 ? WQT : z == 1 ? WKT : z == 2 ? WVT : WOT) +
      (size_t)xb * 65536 + (size_t)kb * 64;

#pragma unroll
  for (int j4 = 0; j4 < 4; ++j4) {
    float4 v = *(const float4*)(srcp + (size_t)kr * srs + q4 * 16 + j4 * 4);
    t[kr][q4 * 16 + j4 * 4 + 0] = v.x;
    t[kr][q4 * 16 + j4 * 4 + 1] = v.y;
    t[kr][q4 * 16 + j4 * 4 + 2] = v.z;
    t[kr][q4 * 16 + j4 * 4 + 3] = v.w;
  }
  __syncthreads();

  const int er = tid >> 2;
  u16x8 lo, hi;
#pragma unroll
  for (int j = 0; j < 8; ++j) lo[j] = f2bf(t[q4 * 16 + j][er]);
#pragma unroll
  for (int j = 0; j < 8; ++j) hi[j] = f2bf(t[q4 * 16 + 8 + j][er]);
  unsigned short* d = dstb + (size_t)er * 1024 + q4 * 16;
  *(u16x8*)d = lo;
  *(u16x8*)(d + 8) = hi;
}

// ---------------------- QKV projection: 256^2 8-phase -----------------------
// LDS map (bytes): buf d in {0,1}: A @ d*65536 (+half*16384), B @ d*65536+32768.
// LDS rows are 128B (BK=64 bf16); chunk swizzle: ch' = ch ^ (row&7), applied
// on the global SOURCE at stage time and on the ds_read address (both-sides).

#define STG(gb, h, dbase, kt)                                                  \
  GLD16((gb) + (size_t)((h) * 128 + slr) * 2048 + (kt) * 128 + sch,            \
        smem + (dbase) + (h) * 16384 + wid * 1024);                            \
  GLD16((gb) + (size_t)((h) * 128 + 64 + slr) * 2048 + (kt) * 128 + sch,       \
        smem + (dbase) + (h) * 16384 + 8192 + wid * 1024);

#define LDA(buf, mq)                                                           \
  _Pragma("unroll") for (int mi = 0; mi < 4; ++mi)                             \
  _Pragma("unroll") for (int ks = 0; ks < 2; ++ks)                             \
    afr[mi][ks] = *(const s16x8*)(smem + (buf) * 65536 + wr * 16384 +          \
        ((mq) * 64 + mi * 16 + c) * 128 + (((ks * 4 + g) ^ (c & 7)) << 4));

#define LDB(buf, nq)                                                           \
  _Pragma("unroll") for (int ni = 0; ni < 2; ++ni)                             \
  _Pragma("unroll") for (int ks = 0; ks < 2; ++ks)                             \
    bfr[(nq) * 2 + ni][ks] = *(const s16x8*)(smem + (buf) * 65536 + 32768 +    \
        (wc >> 1) * 16384 + ((wc & 1) * 64 + ((nq) * 2 + ni) * 16 + c) * 128 + \
        (((ks * 4 + g) ^ (c & 7)) << 4));

#define MMA(mq, nq)                                                            \
  __builtin_amdgcn_s_setprio(1);                                               \
  _Pragma("unroll") for (int ks = 0; ks < 2; ++ks)                             \
  _Pragma("unroll") for (int mi = 0; mi < 4; ++mi)                             \
  _Pragma("unroll") for (int ni = 0; ni < 2; ++ni)                             \
    acc[(mq) * 4 + mi][(nq) * 2 + ni] = mfma16(                                \
        afr[mi][ks], bfr[(nq) * 2 + ni][ks], acc[(mq) * 4 + mi][(nq) * 2 + ni]);\
  __builtin_amdgcn_s_setprio(0);

#define BAR() __builtin_amdgcn_s_barrier()
#define SYNCV()                                                                \
  do {                                                                         \
    asm volatile("s_waitcnt vmcnt(0)" ::: "memory");                           \
    __builtin_amdgcn_s_barrier();                                              \
    __builtin_amdgcn_sched_barrier(0);                                         \
  } while (0)

__global__ __launch_bounds__(512, 2) void gemm_qkv8(
    const unsigned short* __restrict__ Xq, const unsigned short* __restrict__ Xk,
    const unsigned short* __restrict__ Xv,
    const unsigned short* __restrict__ Wqt, const unsigned short* __restrict__ Wkt,
    const unsigned short* __restrict__ Wvt,
    const float* __restrict__ bq, const float* __restrict__ bk,
    const float* __restrict__ bv,
    unsigned short* __restrict__ Qp, unsigned short* __restrict__ Kp,
    unsigned short* __restrict__ Vt) {
  __shared__ char smem[131072];

  const int tid = threadIdx.x, wid = tid >> 6, lane = tid & 63;
  const int g = lane >> 4, c = lane & 15;
  const int wr = wid >> 2, wc = wid & 3;

  // bijective XCD swizzle: 384 blocks = 8 XCDs x 48
  const int L = blockIdx.x;
  const int W = (L & 7) * 48 + (L >> 3);
  const int z = W >> 7, rem = W & 127, by = rem >> 2, bx = rem & 3;
  const int m0 = by * 256, n0 = bx * 256;

  const unsigned short* A  = z == 0 ? Xq : z == 1 ? Xk : Xv;
  const unsigned short* Bt = z == 0 ? Wqt : z == 1 ? Wkt : Wvt;
  const float* bias = z == 0 ? bq : z == 1 ? bk : bv;

  const char* Ab = (const char*)A  + (size_t)m0 * 2048;
  const char* Bb = (const char*)Bt + (size_t)n0 * 2048;

  // staging lane geometry: one GLD16 covers 64 rows (8 rows/wave)
  const int slr = (wid << 3) + ((lane >> 3) & 7);            // local row 0..63
  const int sch = ((lane & 7) ^ ((lane >> 3) & 7)) << 4;     // swizzled src chunk

  f32x4 acc[8][4] = {};
  s16x8 afr[4][2], bfr[4][2];

  // prologue: T0 -> buf0
  STG(Ab, 0, 0, 0); STG(Ab, 1, 0, 0);
  STG(Bb, 0, 32768, 0); STG(Bb, 1, 32768, 0);
  SYNCV();

  for (int it = 0; it < 8; ++it) {
    const int ktB = 2 * it + 1, ktN = 2 * it + 2;
    // ---- phases 1-4: compute buf0 (T 2it); stage T ktB -> buf1 ----
    LDA(0, 0); LDB(0, 0); STG(Ab, 0, 65536, ktB);        BAR(); MMA(0, 0); BAR();
    LDB(0, 1);            STG(Ab, 1, 65536, ktB);        BAR(); MMA(0, 1); BAR();
    LDA(0, 1);            STG(Bb, 0, 65536 + 32768, ktB);BAR(); MMA(1, 0); BAR();
                          STG(Bb, 1, 65536 + 32768, ktB);BAR(); MMA(1, 1); SYNCV();
    // ---- phases 5-8: compute buf1 (T ktB); stage T ktN -> buf0 ----
    LDA(1, 0); LDB(1, 0); if (it < 7) { STG(Ab, 0, 0, ktN); }     BAR(); MMA(0, 0); BAR();
    LDB(1, 1);            if (it < 7) { STG(Ab, 1, 0, ktN); }     BAR(); MMA(0, 1); BAR();
    LDA(1, 1);            if (it < 7) { STG(Bb, 0, 32768, ktN); } BAR(); MMA(1, 0); BAR();
                          if (it < 7) { STG(Bb, 1, 32768, ktN); } BAR(); MMA(1, 1); SYNCV();
  }

  // epilogue: C[m][n] + bias, routed per z (Q scaled, K plain, V transposed)
#pragma unroll
  for (int ni = 0; ni < 4; ++ni) {
    const int n = n0 + wc * 64 + ni * 16 + c;
    const float bn = bias[n];
    const int h = n >> 6, e = n & 63;
#pragma unroll
    for (int mi = 0; mi < 8; ++mi) {
      const int m = m0 + wr * 128 + mi * 16 + 4 * g;
      const int b = m >> 11, s = m & 2047;
      if (z == 2) {
        u16x4 o;
#pragma unroll
        for (int i = 0; i < 4; ++i) o[i] = f2bf(acc[mi][ni][i] + bn);
        *(u16x4*)&Vt[(((size_t)(b * 16 + h) * 64 + e) << 11) + s] = o;
      } else {
        unsigned short* dst = (z == 0) ? Qp : Kp;
        const float scale = (z == 0) ? 0.1803368801111244f : 1.0f;  // log2(e)/8
        const size_t base = (((size_t)(b * 16 + h) << 11) + s) << 6;
#pragma unroll
        for (int i = 0; i < 4; ++i)
          dst[base + (size_t)i * 64 + e] = f2bf((acc[mi][ni][i] + bn) * scale);
      }
    }
  }
}

// ------------------------------- attention ----------------------------------
// (unchanged from R3/R5)
__global__ __launch_bounds__(256, 4) void attn(
    const unsigned short* __restrict__ Qp, const unsigned short* __restrict__ Kp,
    const unsigned short* __restrict__ Vt, const float* __restrict__ hsel,
    unsigned short* __restrict__ Cmb) {
  __shared__ char smem[16384];   // [2 bufs][K 4KB | V 4KB]

  const int tid = threadIdx.x, w = tid >> 6, l = tid & 63, g = l >> 4, c = l & 15;
  const int L  = blockIdx.x;
  const int Lp = (L & 7) * 128 + (L >> 3);   // bijective XCD swizzle
  const int bh = Lp >> 4, qb = Lp & 15;
  const int b = bh >> 4, h = bh & 15;

  float hm = -1e30f, hs = 0.f;
  for (int i = 0; i < 16; ++i) hm = fmaxf(hm, hsel[i]);
  for (int i = 0; i < 16; ++i) hs += __expf(hsel[i] - hm);
  const float hw = __expf(hsel[h] - hm) / hs;

  const size_t qbase = ((size_t)bh * 2048 + qb * 128 + w * 32) * 64;
  s16x8 qf[2][2];
#pragma unroll
  for (int nt = 0; nt < 2; ++nt)
#pragma unroll
    for (int ks = 0; ks < 2; ++ks)
      qf[nt][ks] = *(const s16x8*)(Qp + qbase + (size_t)(nt * 16 + c) * 64 +
                                   ks * 32 + 8 * g);

  f32x4 accc[4][2] = {};           // [et][nt] : ctx^T[e][sq]
  f32x4 lacc[2] = {};              // softmax denominators via ones-MFMA
  const short ob = (short)0x3F80;  // bf16 1.0
  const s16x8 ones = { ob, ob, ob, ob, ob, ob, ob, ob };

  const size_t kbase = (size_t)bh * 2048 * 128;
  const size_t vbase = (size_t)bh * 64 * 4096;
  const int krow = tid >> 3, kslot = tid & 7;
  const size_t kroff = kbase + (size_t)krow * 128 + (size_t)((kslot ^ (krow & 7)) * 16);
  const int vrow = tid >> 2, vslot = tid & 3, vsr = vrow >> 1;
  const int vsch = (((vrow & 1) << 2) | vslot) ^ (vsr & 7);
  const size_t vroff = vbase + (size_t)(vsr * 2 + (vsch >> 2)) * 4096 + (vsch & 3) * 16;

  GLD16((const char*)Kp + kroff, smem + w * 1024);
  GLD16((const char*)Vt + vroff, smem + 4096 + w * 1024);
  __syncthreads();

  for (int it = 0; it < 64; ++it) {
    const int cur = it & 1;
    if (it + 1 < 64) {
      const size_t t0 = (size_t)(it + 1) * 32;
      GLD16((const char*)Kp + kroff + t0 * 128, smem + (cur ^ 1) * 8192 + w * 1024);
      GLD16((const char*)Vt + vroff + t0 * 2,   smem + (cur ^ 1) * 8192 + 4096 + w * 1024);
    }
    const unsigned short* sK = (const unsigned short*)(smem + cur * 8192);
    const unsigned short* sV = (const unsigned short*)(smem + cur * 8192 + 4096);

    f32x4 st[2][2] = {};
#pragma unroll
    for (int ks = 0; ks < 2; ++ks)
#pragma unroll
      for (int mt = 0; mt < 2; ++mt) {
        const int tr = mt * 16 + c;
        s16x8 kf = *(const s16x8*)&sK[tr * 64 + (((4 * ks + g) ^ (tr & 7)) << 3)];
#pragma unroll
        for (int nt = 0; nt < 2; ++nt)
          st[mt][nt] = mfma16(kf, qf[nt][ks], st[mt][nt]);
      }

    s16x8 pf[2];
#pragma unroll
    for (int nt = 0; nt < 2; ++nt) {
#pragma unroll
      for (int mt = 0; mt < 2; ++mt)
#pragma unroll
        for (int i = 0; i < 4; ++i)
          st[mt][nt][i] = __builtin_amdgcn_exp2f(st[mt][nt][i]);   // m == 0

      unsigned a0, a1, b0, b1;
      asm("v_cvt_pk_bf16_f32 %0, %1, %2" : "=v"(a0) : "v"(st[0][nt][0]), "v"(st[0][nt][1]));
      asm("v_cvt_pk_bf16_f32 %0, %1, %2" : "=v"(a1) : "v"(st[0][nt][2]), "v"(st[0][nt][3]));
      asm("v_cvt_pk_bf16_f32 %0, %1, %2" : "=v"(b0) : "v"(st[1][nt][0]), "v"(st[1][nt][1]));
      asm("v_cvt_pk_bf16_f32 %0, %1, %2" : "=v"(b1) : "v"(st[1][nt][2]), "v"(st[1][nt][3]));
      asm("v_permlane32_swap_b32 %0, %1" : "+v"(a0), "+v"(b0));
      asm("v_permlane16_swap_b32 %0, %1" : "+v"(a0), "+v"(b0));
      asm("v_permlane32_swap_b32 %0, %1" : "+v"(a1), "+v"(b1));
      asm("v_permlane16_swap_b32 %0, %1" : "+v"(a1), "+v"(b1));
      u32x4 pd = { a0, a1, b0, b1 };
      pf[nt] = __builtin_bit_cast(s16x8, pd);
      lacc[nt] = mfma16(ones, pf[nt], lacc[nt]);   // += per-row P sums
    }

#pragma unroll
    for (int et = 0; et < 4; ++et) {
      const int er = et * 16 + c;
      const int ch = (((er & 1) << 2) | g) ^ ((er >> 1) & 7);
      s16x8 vf = *(const s16x8*)&sV[(er >> 1) * 64 + ch * 8];
#pragma unroll
      for (int nt = 0; nt < 2; ++nt)
        accc[et][nt] = mfma16(vf, pf[nt], accc[et][nt]);
    }
    __syncthreads();
  }

#pragma unroll
  for (int nt = 0; nt < 2; ++nt) {
    const float sc = hw / lacc[nt][0];
    const int s = qb * 128 + w * 32 + nt * 16 + c;
    unsigned short* dst = Cmb + (((size_t)(b * 2048 + s)) << 10) + h * 64;
#pragma unroll
    for (int et = 0; et < 4; ++et) {
      u16x4 o = { f2bf(accc[et][nt][0] * sc), f2bf(accc[et][nt][1] * sc),
                  f2bf(accc[et][nt][2] * sc), f2bf(accc[et][nt][3] * sc) };
      *(u16x4*)(dst + et * 16 + 4 * g) = o;
    }
  }
}

// ------------------------------ output GEMM ---------------------------------
// (unchanged from R4/R5: 128^2, XCD-panel swizzle + 2-phase dbuf)
#define STAGE_G(BUF, KT)                                                      \
  {                                                                           \
    const int k0q = (KT) * 32;                                                \
    _Pragma("unroll") for (int r = 0; r < 2; ++r) {                           \
      const int row = r * 64 + srow, sr = row >> 1;                           \
      const int sch2 = (((row & 1) << 2) | sslot) ^ (sr & 7);                 \
      const size_t roff =                                                     \
          (size_t)(sr * 2 + (sch2 >> 2)) * 2048 + k0q * 2 + (sch2 & 3) * 16;  \
      GLD16((const char*)A + (size_t)m0 * 2048 + roff,                        \
            (char*)sA[BUF] + r * 4096 + w * 1024);                            \
      GLD16((const char*)Bt + (size_t)n0 * 2048 + roff,                       \
            (char*)sB[BUF] + r * 4096 + w * 1024);                            \
    }                                                                         \
  }

__global__ __launch_bounds__(256, 2) void gemm_out(
    const unsigned short* __restrict__ A, const unsigned short* __restrict__ Bt,
    const float* __restrict__ bo, float* __restrict__ out) {
  const int L = blockIdx.x;
  const int W = (L & 7) * 64 + (L >> 3);
  const int vy = W >> 3, vx = W & 7;

  __shared__ unsigned short sA[2][128 * 32], sB[2][128 * 32];
  const int tid = threadIdx.x, w = tid >> 6, l = tid & 63, g = l >> 4, c = l & 15;
  const int m0 = vy * 128, n0 = vx * 128;
  const int wrow = (w >> 1) * 64, wcol = (w & 1) * 64;
  const int srow = tid >> 2, sslot = tid & 3;

  f32x4 acc[4][4] = {};

  STAGE_G(0, 0);
  __syncthreads();

  for (int kt = 0; kt < 32; ++kt) {
    const int cur = kt & 1;
    if (kt + 1 < 32) STAGE_G(cur ^ 1, kt + 1);
    s16x8 af[4], bfr2[4];
#pragma unroll
    for (int mi = 0; mi < 4; ++mi) {
      const int row = wrow + mi * 16 + c;
      const int ch = (((row & 1) << 2) | g) ^ ((row >> 1) & 7);
      af[mi] = *(const s16x8*)&sA[cur][(row >> 1) * 64 + ch * 8];
    }
#pragma unroll
    for (int ni = 0; ni < 4; ++ni) {
      const int row = wcol + ni * 16 + c;
      const int ch = (((row & 1) << 2) | g) ^ ((row >> 1) & 7);
      bfr2[ni] = *(const s16x8*)&sB[cur][(row >> 1) * 64 + ch * 8];
    }
#pragma unroll
    for (int mi = 0; mi < 4; ++mi)
#pragma unroll
      for (int ni = 0; ni < 4; ++ni)
        acc[mi][ni] = mfma16(af[mi], bfr2[ni], acc[mi][ni]);
    __syncthreads();
  }

#pragma unroll
  for (int ni = 0; ni < 4; ++ni) {
    const int n = n0 + wcol + ni * 16 + c;
    const float bn = bo[n];
#pragma unroll
    for (int mi = 0; mi < 4; ++mi) {
      const int m = m0 + wrow + mi * 16 + 4 * g;
#pragma unroll
      for (int i = 0; i < 4; ++i)
        out[(size_t)(m + i) * 1024 + n] = acc[mi][ni][i] + bn;
    }
  }
}

// ------------------------------- launcher -----------------------------------
extern "C" void kernel_launch(void* const* d_in, const int* in_sizes, int n_in,
                              void* d_out, int out_size, void* d_ws, size_t ws_size,
                              hipStream_t stream) {
  const float* query = (const float*)d_in[0];
  const float* key   = (const float*)d_in[1];
  const float* value = (const float*)d_in[2];
  const float* Wq    = (const float*)d_in[3];
  const float* bq    = (const float*)d_in[4];
  const float* Wk    = (const float*)d_in[5];
  const float* bk    = (const float*)d_in[6];
  const float* Wv    = (const float*)d_in[7];
  const float* bv    = (const float*)d_in[8];
  const float* Wo    = (const float*)d_in[9];
  const float* bo    = (const float*)d_in[10];
  const float* hsel  = (const float*)d_in[11];
  float* out = (float*)d_out;

  char* ws = (char*)d_ws;
  const size_t SZX = 16777216;   // 8192*1024*2
  const size_t SZW = 2097152;    // 1024*1024*2
  unsigned short* XQ  = (unsigned short*)(ws);
  unsigned short* XK  = (unsigned short*)(ws + SZX);
  unsigned short* XV  = (unsigned short*)(ws + 2 * SZX);
  unsigned short* WQT = (unsigned short*)(ws + 3 * SZX);
  unsigned short* WKT = (unsigned short*)(ws + 3 * SZX + SZW);
  unsigned short* WVT = (unsigned short*)(ws + 3 * SZX + 2 * SZW);
  unsigned short* WOT = (unsigned short*)(ws + 3 * SZX + 3 * SZW);
  unsigned short* QP  = (unsigned short*)(ws + 3 * SZX + 4 * SZW);
  unsigned short* KP  = (unsigned short*)(ws + 4 * SZX + 4 * SZW);
  unsigned short* VTP = (unsigned short*)(ws + 5 * SZX + 4 * SZW);
  unsigned short* CMB = (unsigned short*)(ws + 6 * SZX + 4 * SZW);

  cvt_all<<<dim3(4096, 3), 256, 0, stream>>>(query, key, value, XQ, XK, XV);
  pack_all<<<dim3(16, 16, 4), 256, 0, stream>>>(Wq, Wk, Wv, Wo, WQT, WKT, WVT, WOT);
  gemm_qkv8<<<384, 512, 0, stream>>>(XQ, XK, XV, WQT, WKT, WVT,
                                     bq, bk, bv, QP, KP, VTP);
  attn<<<1024, 256, 0, stream>>>(QP, KP, VTP, hsel, CMB);
  gemm_out<<<512, 256, 0, stream>>>(CMB, WOT, bo, out);
}